// Round 8
// baseline (33.311 us; speedup 1.0000x reference)
//
#include <hip/hip_runtime.h>

// Grouped conv1d over W + roll(+1) along H, bf16 MFMA 32x32x16, persistent.
// x: (128, 48, 28, 28) f32, channel = g*24+ci
// w: (24, 96, 7) f32, w[ci][o][k], shared across the 2 groups
// out: (128, 192, 28, 28) f32, channel = g*96+o
//
// R8: SWAPPED GEMM: A = weights (M=96 channels), B = x (N=112 positions),
// K=168 pad 176 (11 steps of 16). D (32x32, verified m74/m101): col=lane&31 =
// position -> each store instr writes 2 channels x 128B contiguous aligned
// runs = 4 full lines (R7's lane-scatter was ~17 chunks/instr). A in 44 VGPR
// (built once from LDS w-bounce); B = ds_read_b128 from k-permuted xs (R7
// layout). Grid 512 = (b,g,s): 2 blocks/CU so barriers overlap compute.
// Block owns output rows 4ht..4ht+3 for its tiles; src rows (4ht+hl-1) mod 28
// absorb the roll.
// k-permutation (A and B must agree): q = 2*ks + (lane>>5), slots j=0..7:
//   q<21: kw = q/3, ci = (q%3)*8 + j ; q=21: A=0 (B reads benign garbage).

typedef __attribute__((ext_vector_type(8))) short short8;
typedef __attribute__((ext_vector_type(16))) float float16v;

#define B_     128
#define H_     28
#define W_     28
#define HW_    784
#define COUT_  96
#define K_     7
#define KQ     11     // k-steps of 16

// float -> bf16 bits, RNE
static __device__ __forceinline__ unsigned f2bf_u(float f) {
    union { float f; unsigned u; } v; v.f = f;
    return (v.u + 0x7fffu + ((v.u >> 16) & 1u)) >> 16;
}

__global__ __launch_bounds__(384, 3)
void conv_mfma_kernel(const float* __restrict__ x,
                      const float* __restrict__ w,
                      float* __restrict__ out) {
    const int bid = blockIdx.x;            // 512 = b*4 + g*2 + s
    const int s   = bid & 1;
    const int g   = (bid >> 1) & 1;
    const int b   = bid >> 2;
    const int ht0 = s ? 4 : 0;
    const int ntile = s ? 3 : 4;           // tiles this block owns
    const int tid  = threadIdx.x;
    const int lane = tid & 63;
    const int wv   = tid >> 6;             // 0..5
    const int col  = lane & 31;
    const int half = lane >> 5;
    const int mt   = wv >> 1;              // 0..2 : 32-channel M-tile
    const int np   = wv & 1;               // N-pair: nt {2np, 2np+1}

    // LDS: prologue wbf[24][96][7] bf16 (32256B); then xs dbuf 2x6912B aliased.
    __shared__ __align__(16) char smem[32256];
    short* wbf = (short*)smem;
    short* xs0 = (short*)smem;             // [4][36][24] bf16
    short* xs1 = (short*)(smem + 6912);

    // ---- w -> bf16 LDS bounce (coalesced float4)
    for (int i = tid; i < 4032; i += 384) {
        const float4 v = ((const float4*)w)[i];
        ((uint2*)wbf)[i] = make_uint2(f2bf_u(v.x) | (f2bf_u(v.y) << 16),
                                      f2bf_u(v.z) | (f2bf_u(v.w) << 16));
    }
    __syncthreads();

    // ---- A-frags (weights) -> 44 VGPR. Lane: channel ch = mt*32+col,
    // k-slots q = 2*ks + half, elems j -> (kw, ci0+j).
    const int ch = mt * 32 + col;
    short8 af[KQ];
#pragma unroll
    for (int ks = 0; ks < KQ; ++ks) {
        const int q = 2 * ks + half;
        if (q < 21) {
            const int kw  = (q * 11) >> 5;         // q/3
            const int ci0 = (q - 3 * kw) * 8;
#pragma unroll
            for (int j = 0; j < 8; ++j)
                af[ks][j] = wbf[((ci0 + j) * COUT_ + ch) * K_ + kw];
        } else {
#pragma unroll
            for (int j = 0; j < 8; ++j) af[ks][j] = 0;   // K zero-pad
        }
    }
    __syncthreads();    // all waves done with wbf before xs overwrites it

    // ---- B-side LDS offsets (same k-permutation)
    int koff[KQ];
#pragma unroll
    for (int ks = 0; ks < KQ; ++ks) {
        const int q   = 2 * ks + half;
        const int kw  = (q * 11) >> 5;
        const int ci0 = (q - 3 * kw) * 8;
        koff[ks] = kw * 24 + ci0;                  // shorts; 16B-aligned
    }
    const int p0  = np * 64 + col;                 // position of acc0 (<112)
    const int p1  = p0 + 32;                       // position of acc1 (may pad)
    const int hl0 = p0 / 28, t0 = p0 - hl0 * 28;
    const int hl1 = p1 / 28, t1 = p1 - hl1 * 28;   // hl1=4 possible: benign
    const int pb0 = (hl0 * 36 + t0) * 24;
    const int pb1 = (hl1 * 36 + t1) * 24;

    // ---- staging helpers (R7): 1728 packed dwords per tile
    float v0r[5], v1r[5];
    auto stage_load = [&](int ht) {
#pragma unroll
        for (int it = 0; it < 5; ++it) {
            const int idx = tid + it * 384;
            if (idx < 1728) {
                const int p  = idx % 36;
                const int r  = idx / 36;
                const int cp = r % 12;
                const int hl = r / 12;
                const int ws = p - 3;
                const int rsrc = (4 * ht + hl + 27) % 28;
                float a0 = 0.0f, a1 = 0.0f;
                if (ws >= 0 && ws < W_) {
                    const size_t base =
                        ((size_t)(b * 48 + g * 24 + cp * 2) * H_ + rsrc) * W_ + ws;
                    a0 = x[base];
                    a1 = x[base + (size_t)HW_];
                }
                v0r[it] = a0; v1r[it] = a1;
            }
        }
    };
    auto stage_write = [&](short* xs) {
#pragma unroll
        for (int it = 0; it < 5; ++it) {
            const int idx = tid + it * 384;
            if (idx < 1728) {
                const int p  = idx % 36;
                const int r  = idx / 36;
                const int cp = r % 12;
                const int hl = r / 12;
                ((unsigned*)xs)[(hl * 36 + p) * 12 + cp] =
                    f2bf_u(v0r[it]) | (f2bf_u(v1r[it]) << 16);
            }
        }
    };

    // out base for this wave: channels mt*32 + 4*half + {(r&3)+8*(r>>2)}
    float* ob = out + ((size_t)(b * 192 + g * COUT_ + mt * 32 + 4 * half)) * HW_;

    // ---- pipelined tile loop
    stage_load(ht0);
    stage_write(xs0);
    __syncthreads();
    for (int tix = 0; tix < ntile; ++tix) {
        const int ht = ht0 + tix;
        const short* cur = (tix & 1) ? xs1 : xs0;
        short*       nxt = (tix & 1) ? xs0 : xs1;
        if (tix < ntile - 1) stage_load(ht + 1);

        float16v acc0 = (float16v)(0.0f);
        float16v acc1 = (float16v)(0.0f);
#pragma unroll
        for (int ks = 0; ks < KQ; ++ks) {
            const short8 b0 = *(const short8*)&cur[pb0 + koff[ks]];
            const short8 b1 = *(const short8*)&cur[pb1 + koff[ks]];
            acc0 = __builtin_amdgcn_mfma_f32_32x32x16_bf16(af[ks], b0, acc0, 0, 0, 0);
            acc1 = __builtin_amdgcn_mfma_f32_32x32x16_bf16(af[ks], b1, acc1, 0, 0, 0);
        }

        // Stores: per r, lanes write 2 channels x 32 consecutive positions
        // (128B aligned runs). Tile's positions are contiguous: off = ht*112+p.
        float* obt = ob + ht * 112;
#pragma unroll
        for (int r = 0; r < 16; ++r) {
            const int choff = ((r & 3) + 8 * (r >> 2)) * HW_;
            obt[choff + p0] = acc0[r];
        }
        if (p1 < 112) {
#pragma unroll
            for (int r = 0; r < 16; ++r) {
                const int choff = ((r & 3) + 8 * (r >> 2)) * HW_;
                obt[choff + p1] = acc1[r];
            }
        }

        if (tix < ntile - 1) stage_write(nxt);
        __syncthreads();
    }
}

extern "C" void kernel_launch(void* const* d_in, const int* in_sizes, int n_in,
                              void* d_out, int out_size, void* d_ws, size_t ws_size,
                              hipStream_t stream) {
    const float* x = (const float*)d_in[0];
    const float* w = (const float*)d_in[1];
    float* out = (float*)d_out;
    conv_mfma_kernel<<<B_ * 4, 384, 0, stream>>>(x, w, out);
}

// Round 9
// 27.894 us; speedup vs baseline: 1.1942x; 1.1942x over previous
//
#include <hip/hip_runtime.h>

// Grouped conv1d over W + roll(+1) along H, bf16 MFMA. Persistent, 2 blk/CU.
// x: (128, 48, 28, 28) f32, channel = g*24+ci
// w: (24, 96, 7) f32, w[ci][o][k], shared across the 2 groups
// out: (128, 192, 28, 28) f32, channel = g*96+o
//
// R9 = R7 structure (best: 28.9us) + grid 512: block (b,g,s) takes interleaved
// tiles {s, s+2, ...} so 2 blocks/CU overlap each other's stage/barrier phases
// (R7's 1 blk/CU exposed the serial tail every tile; R8 showed 2 blk/CU loses
// only 4us even with a worse epilogue).
// GEMM per tile: M=112 (4 output rows x 28 W), N=96, K=168 pad 192.
// k-permutation (A and B must match): q = ks*4+kgrp (0..23);
//   q<21: k=q/3, ci=(q%3)*8+j ; q>=21: zero (B side).
// Epilogue: D-quad j=0..3 = 4 consecutive t in one row -> float4; lanes
// {cgrp, kgrp} tile 16 channels x 64B full lines per wave-store (measured
// ideal WRITE_SIZE 75.3MB in R6/R7).

typedef __attribute__((ext_vector_type(8))) short short8;
typedef __attribute__((ext_vector_type(4))) float float4v;

#define B_     128
#define H_     28
#define W_     28
#define CIN_   24
#define COUT_  96
#define K_     7
#define KSTEPS 6
#define NT_    6
#define MT_    7
#define HW_    784

// float -> bf16 bits, RNE
static __device__ __forceinline__ unsigned f2bf_u(float f) {
    union { float f; unsigned u; } v; v.f = f;
    return (v.u + 0x7fffu + ((v.u >> 16) & 1u)) >> 16;
}

__global__ __launch_bounds__(384, 2)
void conv_mfma_kernel(const float* __restrict__ x,
                      const float* __restrict__ w,
                      float* __restrict__ out) {
    const int bid  = blockIdx.x;          // 512 = b*4 + g*2 + s
    const int s    = bid & 1;
    const int g    = (bid >> 1) & 1;
    const int b    = bid >> 2;
    const int ntile = 4 - s;              // s=0: tiles 0,2,4,6 ; s=1: 1,3,5
    const int tid  = threadIdx.x;
    const int lane = tid & 63;
    const int nt   = tid >> 6;            // wave = N-tile, 0..5
    const int cgrp = lane & 15;
    const int kgrp = lane >> 4;

    // LDS union: prologue wbf[24][96][7] bf16 (32256B); then xs dbuf 2x6912B.
    __shared__ __align__(16) char smem[32256];
    short* wbf = (short*)smem;
    short* xs0 = (short*)smem;            // [4][36][24] bf16
    short* xs1 = (short*)(smem + 6912);

    // ---- wbf: coalesced w read (16128 floats = 4032 float4), bf16 convert
    for (int i = tid; i < 4032; i += 384) {
        const float4 v = ((const float4*)w)[i];
        const unsigned lo = f2bf_u(v.x) | (f2bf_u(v.y) << 16);
        const unsigned hi = f2bf_u(v.z) | (f2bf_u(v.w) << 16);
        ((uint2*)wbf)[i] = make_uint2(lo, hi);
    }
    __syncthreads();

    // ---- B fragments -> 24 VGPR (48 ds_read_u16/lane, once per block)
    const int c_out = nt * 16 + cgrp;     // 0..95 within group
    short8 br[KSTEPS];
#pragma unroll
    for (int ks = 0; ks < KSTEPS; ++ks) {
        const int q = ks * 4 + kgrp;
        if (q < 21) {
            const int k   = (q * 11) >> 5;        // q/3
            const int ci0 = (q - 3 * k) * 8;
#pragma unroll
            for (int j = 0; j < 8; ++j)
                br[ks][j] = wbf[((ci0 + j) * COUT_ + c_out) * K_ + k];
        } else {
#pragma unroll
            for (int j = 0; j < 8; ++j) br[ks][j] = 0;  // zero-pad K
        }
    }
    __syncthreads();   // done reading wbf; xs buffers may overwrite it

    // Per-lane k-step LDS offsets (A side of the shared k permutation)
    int koff[KSTEPS];
#pragma unroll
    for (int ks = 0; ks < KSTEPS; ++ks) {
        const int q   = ks * 4 + kgrp;
        const int k   = (q * 11) >> 5;
        const int ci0 = (q - 3 * k) * 8;
        koff[ks] = k * 24 + ci0;
    }

    float* cbase = out + ((size_t)(b * 192 + g * COUT_ + c_out)) * HW_;

    // ---- staging helpers: 1728 packed dwords per tile, 5 iters/thread
    float v0r[5], v1r[5];
    auto stage_load = [&](int ht) {
#pragma unroll
        for (int it = 0; it < 5; ++it) {
            const int idx = tid + it * 384;
            if (idx < 1728) {
                const int p  = idx % 36;
                const int r  = idx / 36;
                const int cp = r % 12;
                const int hl = r / 12;
                const int ws = p - 3;
                const int rsrc = (4 * ht + hl + 27) % 28;
                float a0 = 0.0f, a1 = 0.0f;
                if (ws >= 0 && ws < W_) {
                    const size_t base =
                        ((size_t)(b * 48 + g * CIN_ + cp * 2) * H_ + rsrc) * W_ + ws;
                    a0 = x[base];
                    a1 = x[base + (size_t)HW_];
                }
                v0r[it] = a0; v1r[it] = a1;
            }
        }
    };
    auto stage_write = [&](short* xs) {
#pragma unroll
        for (int it = 0; it < 5; ++it) {
            const int idx = tid + it * 384;
            if (idx < 1728) {
                const int p  = idx % 36;
                const int r  = idx / 36;
                const int cp = r % 12;
                const int hl = r / 12;
                ((unsigned*)xs)[(hl * 36 + p) * 12 + cp] =
                    f2bf_u(v0r[it]) | (f2bf_u(v1r[it]) << 16);
            }
        }
    };
    auto compute_tile = [&](const short* xs, int ht) {
#pragma unroll
        for (int mt = 0; mt < MT_; ++mt) {
            const int mA = mt * 16 + cgrp;
            const int hA = mA / 28;
            const int tA = mA - hA * 28;
            const int abase = (hA * 36 + tA) * 24;
            float4v acc = (float4v)(0.0f);
#pragma unroll
            for (int ks = 0; ks < KSTEPS; ++ks) {
                const short8 a = *(const short8*)&xs[abase + koff[ks]];
                acc = __builtin_amdgcn_mfma_f32_16x16x32_bf16(a, br[ks], acc, 0, 0, 0);
            }
            // D-quad j=0..3 = 4 consecutive t in one h-row (m0 % 4 == 0, 4|28)
            const int m0 = mt * 16 + kgrp * 4;
            const int hl = m0 / 28;
            const int t0 = m0 - hl * 28;
            const int hd = 4 * ht + hl;
            float4 v; v.x = acc[0]; v.y = acc[1]; v.z = acc[2]; v.w = acc[3];
            *(float4*)&cbase[hd * W_ + t0] = v;
        }
    };

    // ---- pipelined tile loop over this block's interleaved tiles
    stage_load(s);
    stage_write(xs0);
    __syncthreads();
    for (int tix = 0; tix < ntile; ++tix) {
        const int ht = s + 2 * tix;
        const short* cur = (tix & 1) ? xs1 : xs0;
        short*       nxt = (tix & 1) ? xs0 : xs1;
        if (tix < ntile - 1) stage_load(ht + 2);   // issue next tile's loads
        compute_tile(cur, ht);                     // hides load latency
        if (tix < ntile - 1) stage_write(nxt);     // vmcnt-wait, cvt, ds_write
        __syncthreads();
    }
}

extern "C" void kernel_launch(void* const* d_in, const int* in_sizes, int n_in,
                              void* d_out, int out_size, void* d_ws, size_t ws_size,
                              hipStream_t stream) {
    const float* x = (const float*)d_in[0];
    const float* w = (const float*)d_in[1];
    float* out = (float*)d_out;
    conv_mfma_kernel<<<B_ * 4, 384, 0, stream>>>(x, w, out);
}